// Round 2
// baseline (1095.434 us; speedup 1.0000x reference)
//
#include <hip/hip_runtime.h>

#define N_TOK 16384
#define DIM 2048
#define KCLS 64
#define JRANGES 32
#define RANGE 512   // N_TOK / JRANGES
#define GRP 8       // classes per block group
#define NGRP 8      // KCLS / GRP
#define EPS 1e-8f

__device__ __forceinline__ float wred64(float v) {
#pragma unroll
    for (int o = 32; o > 0; o >>= 1) v += __shfl_xor(v, o, 64);
    return v;
}

// ---------------------------------------------------------------------------
// Kernel 0: sniff labels dtype (int64 vs int32) and normalize to int32 in ws.
// int64 little-endian labels look like [v,0,v,0,...] as int32; random int32
// labels in [0,64) make the all-(hi==0) pattern astronomically unlikely.
__global__ __launch_bounds__(256) void fix_labels_kernel(
    const int* __restrict__ raw, int* __restrict__ lab) {
    __shared__ int not64;
    int t = threadIdx.x;
    if (t == 0) not64 = 0;
    __syncthreads();
    int lo = raw[2 * t], hi = raw[2 * t + 1];
    if (hi != 0 || lo < 0 || lo >= KCLS) atomicOr(&not64, 1);
    __syncthreads();
    int is64 = !not64;
    for (int n = t; n < N_TOK; n += 256)
        lab[n] = is64 ? raw[2 * n] : raw[n];
}

// ---------------------------------------------------------------------------
// Kernel 1: per-token squared norm and inverse clamped norm. One wave/token.
__global__ __launch_bounds__(256) void norms_kernel(
    const float* __restrict__ x, float* __restrict__ vnorm2,
    float* __restrict__ nvinv) {
    int wid = threadIdx.x >> 6, lane = threadIdx.x & 63;
    int n = blockIdx.x * 4 + wid;
    const float* v = x + (size_t)n * DIM;
    float p = 0.f;
#pragma unroll
    for (int it = 0; it < 8; it++) {
        int d = it * 256 + lane * 4;
        float4 a = *(const float4*)(v + d);
        p = fmaf(a.x, a.x, p); p = fmaf(a.y, a.y, p);
        p = fmaf(a.z, a.z, p); p = fmaf(a.w, a.w, p);
    }
    p = wred64(p);
    if (lane == 0) {
        vnorm2[n] = p;
        nvinv[n] = 1.0f / fmaxf(sqrtf(p), EPS);
    }
}

// ---------------------------------------------------------------------------
// Kernel 2: stable bucket of token positions by class. Single block.
__global__ __launch_bounds__(1024) void bucket_kernel(
    const int* __restrict__ lab, int* __restrict__ pos,
    int* __restrict__ cls_off, int* __restrict__ cls_cnt) {
    __shared__ int cnt[16][KCLS];
    __shared__ int tot[KCLS];
    __shared__ int off[KCLS];
    int t = threadIdx.x;
    int c = t >> 6, k = t & 63;
    const int CH = N_TOK / 16;
    int base = c * CH;
    int cc = 0;
    for (int i = 0; i < CH; i++) cc += (lab[base + i] == k) ? 1 : 0;
    cnt[c][k] = cc;
    __syncthreads();
    if (t < KCLS) {
        int s = 0;
        for (int c2 = 0; c2 < 16; c2++) s += cnt[c2][t];
        tot[t] = s;
        cls_cnt[t] = s;
    }
    __syncthreads();
    if (t == 0) {
        int run = 0;
        for (int k2 = 0; k2 < KCLS; k2++) { off[k2] = run; run += tot[k2]; }
    }
    __syncthreads();
    if (t < KCLS) cls_off[t] = off[t];
    int st = off[k];
    for (int c2 = 0; c2 < c; c2++) st += cnt[c2][k];
    for (int i = 0; i < CH; i++)
        if (lab[base + i] == k) pos[st++] = base + i;
}

// ---------------------------------------------------------------------------
// Kernel 3: per-(range, class) partial sum of class-k token vectors.
__global__ __launch_bounds__(256) void partials_kernel(
    const float* __restrict__ x, const int* __restrict__ pos,
    const int* __restrict__ cls_off, const int* __restrict__ cls_cnt,
    float* __restrict__ spart, int* __restrict__ cnt_range) {
    int bid = blockIdx.x;
    int k = bid & 63, j = bid >> 6;
    int t = threadIdx.x;
    int offk = cls_off[k], ck = cls_cnt[k];
    const int* pk = pos + offk;
    int lo = 0, hi = ck, v0 = j * RANGE;
    while (lo < hi) { int m = (lo + hi) >> 1; if (pk[m] < v0) lo = m + 1; else hi = m; }
    int is = lo;
    hi = ck; int v1 = (j + 1) * RANGE;
    while (lo < hi) { int m = (lo + hi) >> 1; if (pk[m] < v1) lo = m + 1; else hi = m; }
    int ie = lo;
    float4 a = {0, 0, 0, 0}, b = {0, 0, 0, 0};
    for (int i = is; i < ie; i++) {
        const float* r = x + (size_t)pk[i] * DIM;
        float4 xa = *(const float4*)(r + t * 4);
        float4 xb = *(const float4*)(r + 1024 + t * 4);
        a.x += xa.x; a.y += xa.y; a.z += xa.z; a.w += xa.w;
        b.x += xb.x; b.y += xb.y; b.z += xb.z; b.w += xb.w;
    }
    float* dst = spart + ((size_t)j * KCLS + k) * DIM;
    *(float4*)(dst + t * 4) = a;
    *(float4*)(dst + 1024 + t * 4) = b;
    if (t == 0) cnt_range[j * KCLS + k] = ie - is;
}

// ---------------------------------------------------------------------------
// Kernel 4: in-place exclusive scan over ranges -> boundary snapshots.
// snapshot[j][k] = initial class_avgs[k] if no class-k token before range j,
// else sum of class-k tokens before range j. Also cnt_before[j][k].
__global__ __launch_bounds__(256) void scan_kernel(
    const float* __restrict__ avgs, float* __restrict__ spart,
    const int* __restrict__ cnt_range, int* __restrict__ cnt_before) {
    int t = blockIdx.x * 256 + threadIdx.x;  // 32768 threads
    int k = t >> 9;
    int d4 = t & 511;
    int d = d4 * 4;
    float4 run = {0, 0, 0, 0};
    int cb = 0;
    float4 init = *(const float4*)(avgs + (size_t)k * DIM + d);
    for (int j = 0; j < JRANGES; j++) {
        size_t idx = ((size_t)j * KCLS + k) * DIM + d;
        float4 part = *(const float4*)(spart + idx);
        float4 w = (cb == 0) ? init : run;
        *(float4*)(spart + idx) = w;
        if (d4 == 0) cnt_before[j * KCLS + k] = cb;
        run.x += part.x; run.y += part.y; run.z += part.z; run.w += part.w;
        cb += cnt_range[j * KCLS + k];
    }
}

// ---------------------------------------------------------------------------
// Kernel 5: main. One block per (class-group g, token-range j). 8 prototypes
// in LDS; walk 512 tokens in order; wave-per-token dot against 8 prototypes;
// running-mean update (as prefix sum) on group-class tokens.
__global__ __launch_bounds__(256) void main_kernel(
    const float* __restrict__ x, const int* __restrict__ lab,
    const float* __restrict__ snap, const int* __restrict__ cnt_before,
    const float* __restrict__ vnorm2, const float* __restrict__ nvinv,
    float* __restrict__ out) {
    __shared__ float S[GRP][DIM];          // 64 KB
    __shared__ float norm2[GRP];
    __shared__ float rawd[GRP];
    __shared__ float wsum[4][GRP];
    __shared__ unsigned char lbl[RANGE];

    int bid = blockIdx.x;
    int g = bid & 7, j = bid >> 3;
    int g8 = g * GRP;
    int start = j * RANGE;
    int t = threadIdx.x;
    int lane = t & 63, wid = t >> 6;

    for (int i = t; i < RANGE; i += 256) lbl[i] = (unsigned char)lab[start + i];
#pragma unroll
    for (int c = 0; c < GRP; c++) {
        const float* src = snap + ((size_t)j * KCLS + g8 + c) * DIM;
        *(float4*)&S[c][t * 4] = *(const float4*)(src + t * 4);
        *(float4*)&S[c][1024 + t * 4] = *(const float4*)(src + 1024 + t * 4);
    }
    // per-thread virgin bitmask (identical in all threads -> no LDS race)
    unsigned vmask = 0;
#pragma unroll
    for (int c = 0; c < GRP; c++)
        if (cnt_before[j * KCLS + g8 + c] == 0) vmask |= (1u << c);
    __syncthreads();

    // fresh norm^2 of the 8 prototypes
    float p[GRP];
#pragma unroll
    for (int c = 0; c < GRP; c++) p[c] = 0.f;
    for (int d = t; d < DIM; d += 256) {
#pragma unroll
        for (int c = 0; c < GRP; c++) { float v = S[c][d]; p[c] = fmaf(v, v, p[c]); }
    }
#pragma unroll
    for (int c = 0; c < GRP; c++) {
        float s = wred64(p[c]);
        if (lane == 0) wsum[wid][c] = s;
    }
    __syncthreads();
    if (t < GRP) norm2[t] = wsum[0][t] + wsum[1][t] + wsum[2][t] + wsum[3][t];
    __syncthreads();

    int cur = 0;
    while (cur < RANGE) {
        // next token whose class is in this group (uniform across threads)
        int evp = cur;
        while (evp < RANGE && (lbl[evp] >> 3) != g) evp++;
        int segLast = (evp < RANGE) ? evp : (RANGE - 1);

        for (int rel = cur + wid; rel <= segLast; rel += 4) {
            int n = start + rel;
            const float* v = x + (size_t)n * DIM;
            float part[GRP];
#pragma unroll
            for (int c = 0; c < GRP; c++) part[c] = 0.f;
#pragma unroll
            for (int it = 0; it < 8; it++) {
                int d = it * 256 + lane * 4;
                float4 xv = *(const float4*)(v + d);
#pragma unroll
                for (int c = 0; c < GRP; c++) {
                    float4 s4 = *(const float4*)&S[c][d];
                    part[c] = fmaf(xv.x, s4.x, part[c]);
                    part[c] = fmaf(xv.y, s4.y, part[c]);
                    part[c] = fmaf(xv.z, s4.z, part[c]);
                    part[c] = fmaf(xv.w, s4.w, part[c]);
                }
            }
            float outv = 0.f;
#pragma unroll
            for (int c = 0; c < GRP; c++) {
                float s = wred64(part[c]);
                if (lane == c) outv = s;
            }
            if (rel == evp && lane < GRP) rawd[lane] = outv;  // raw dot for norm update
            if (lane < GRP) {
                float na = fmaxf(sqrtf(norm2[lane]), EPS);
                out[(size_t)n * KCLS + g8 + lane] = outv / na * nvinv[n];
            }
        }
        __syncthreads();
        if (evp < RANGE) {
            int ce = lbl[evp] & 7;
            int ne = start + evp;
            const float* v = x + (size_t)ne * DIM;
            bool vg = (vmask >> ce) & 1u;
            if (vg) {
                // first-ever token of this class: prototype := vec
                *(float4*)&S[ce][t * 4] = *(const float4*)(v + t * 4);
                *(float4*)&S[ce][1024 + t * 4] = *(const float4*)(v + 1024 + t * 4);
                if (t == 0) norm2[ce] = vnorm2[ne];
            } else {
                float4 xa = *(const float4*)(v + t * 4);
                float4 xb = *(const float4*)(v + 1024 + t * 4);
                float4 sa = *(float4*)&S[ce][t * 4];
                float4 sb = *(float4*)&S[ce][1024 + t * 4];
                sa.x += xa.x; sa.y += xa.y; sa.z += xa.z; sa.w += xa.w;
                sb.x += xb.x; sb.y += xb.y; sb.z += xb.z; sb.w += xb.w;
                *(float4*)&S[ce][t * 4] = sa;
                *(float4*)&S[ce][1024 + t * 4] = sb;
                if (t == 0) norm2[ce] += 2.0f * rawd[ce] + vnorm2[ne];
            }
            vmask &= ~(1u << ce);
            __syncthreads();
        }
        cur = evp + 1;
    }
}

// ---------------------------------------------------------------------------
extern "C" void kernel_launch(void* const* d_in, const int* in_sizes, int n_in,
                              void* d_out, int out_size, void* d_ws, size_t ws_size,
                              hipStream_t stream) {
    const float* inputs = (const float*)d_in[0];
    const float* class_avgs = (const float*)d_in[1];
    const int* labels_raw = (const int*)d_in[2];
    float* out = (float*)d_out;
    char* ws = (char*)d_ws;

    size_t off = 0;
    int* lab = (int*)(ws + off);        off += (size_t)N_TOK * 4;
    float* vnorm2 = (float*)(ws + off); off += (size_t)N_TOK * 4;
    float* nvinv = (float*)(ws + off);  off += (size_t)N_TOK * 4;
    int* pos = (int*)(ws + off);        off += (size_t)N_TOK * 4;
    int* cls_off = (int*)(ws + off);    off += 256;
    int* cls_cnt = (int*)(ws + off);    off += 256;
    int* cnt_range = (int*)(ws + off);  off += (size_t)JRANGES * KCLS * 4;
    int* cnt_before = (int*)(ws + off); off += (size_t)JRANGES * KCLS * 4;
    off = (off + 255) & ~(size_t)255;
    float* spart = (float*)(ws + off);  // JRANGES*KCLS*DIM floats = 16 MB

    fix_labels_kernel<<<1, 256, 0, stream>>>(labels_raw, lab);
    norms_kernel<<<N_TOK / 4, 256, 0, stream>>>(inputs, vnorm2, nvinv);
    bucket_kernel<<<1, 1024, 0, stream>>>(lab, pos, cls_off, cls_cnt);
    partials_kernel<<<JRANGES * KCLS, 256, 0, stream>>>(inputs, pos, cls_off,
                                                        cls_cnt, spart, cnt_range);
    scan_kernel<<<(KCLS * (DIM / 4)) / 256, 256, 0, stream>>>(class_avgs, spart,
                                                              cnt_range, cnt_before);
    main_kernel<<<NGRP * JRANGES, 256, 0, stream>>>(inputs, lab, spart, cnt_before,
                                                    vnorm2, nvinv, out);
}

// Round 3
// 685.423 us; speedup vs baseline: 1.5982x; 1.5982x over previous
//
#include <hip/hip_runtime.h>

#define N_TOK 16384
#define DIM 2048
#define KCLS 64
#define JRANGES 32
#define RANGE 512   // N_TOK / JRANGES
#define GRP 8       // classes per block group
#define NGRP 8      // KCLS / GRP
#define C_TOK 4     // tokens per staged chunk (== waves per block)
#define EPS 1e-8f

__device__ __forceinline__ float wred64(float v) {
#pragma unroll
    for (int o = 32; o > 0; o >>= 1) v += __shfl_xor(v, o, 64);
    return v;
}

// barrier that orders LDS only (does NOT drain vmcnt -> keeps async staging in flight)
__device__ __forceinline__ void lds_barrier() {
    asm volatile("s_waitcnt lgkmcnt(0)" ::: "memory");
    __builtin_amdgcn_s_barrier();
}

// ---------------------------------------------------------------------------
// Kernel 0: sniff labels dtype (int64 vs int32) and normalize to int32 in ws.
__global__ __launch_bounds__(256) void fix_labels_kernel(
    const int* __restrict__ raw, int* __restrict__ lab) {
    __shared__ int not64;
    int t = threadIdx.x;
    if (t == 0) not64 = 0;
    __syncthreads();
    int lo = raw[2 * t], hi = raw[2 * t + 1];
    if (hi != 0 || lo < 0 || lo >= KCLS) atomicOr(&not64, 1);
    __syncthreads();
    int is64 = !not64;
    for (int n = t; n < N_TOK; n += 256)
        lab[n] = is64 ? raw[2 * n] : raw[n];
}

// ---------------------------------------------------------------------------
// Kernel 1: per-token squared norm and inverse clamped norm. One wave/token.
__global__ __launch_bounds__(256) void norms_kernel(
    const float* __restrict__ x, float* __restrict__ vnorm2,
    float* __restrict__ nvinv) {
    int wid = threadIdx.x >> 6, lane = threadIdx.x & 63;
    int n = blockIdx.x * 4 + wid;
    const float* v = x + (size_t)n * DIM;
    float p = 0.f;
#pragma unroll
    for (int it = 0; it < 8; it++) {
        int d = it * 256 + lane * 4;
        float4 a = *(const float4*)(v + d);
        p = fmaf(a.x, a.x, p); p = fmaf(a.y, a.y, p);
        p = fmaf(a.z, a.z, p); p = fmaf(a.w, a.w, p);
    }
    p = wred64(p);
    if (lane == 0) {
        vnorm2[n] = p;
        nvinv[n] = 1.0f / fmaxf(sqrtf(p), EPS);
    }
}

// ---------------------------------------------------------------------------
// Kernel 2: stable bucket of token positions by class. Single block.
__global__ __launch_bounds__(1024) void bucket_kernel(
    const int* __restrict__ lab, int* __restrict__ pos,
    int* __restrict__ cls_off, int* __restrict__ cls_cnt) {
    __shared__ int cnt[16][KCLS];
    __shared__ int tot[KCLS];
    __shared__ int off[KCLS];
    int t = threadIdx.x;
    int c = t >> 6, k = t & 63;
    const int CH = N_TOK / 16;
    int base = c * CH;
    int cc = 0;
    for (int i = 0; i < CH; i++) cc += (lab[base + i] == k) ? 1 : 0;
    cnt[c][k] = cc;
    __syncthreads();
    if (t < KCLS) {
        int s = 0;
        for (int c2 = 0; c2 < 16; c2++) s += cnt[c2][t];
        tot[t] = s;
        cls_cnt[t] = s;
    }
    __syncthreads();
    if (t == 0) {
        int run = 0;
        for (int k2 = 0; k2 < KCLS; k2++) { off[k2] = run; run += tot[k2]; }
    }
    __syncthreads();
    if (t < KCLS) cls_off[t] = off[t];
    int st = off[k];
    for (int c2 = 0; c2 < c; c2++) st += cnt[c2][k];
    for (int i = 0; i < CH; i++)
        if (lab[base + i] == k) pos[st++] = base + i;
}

// ---------------------------------------------------------------------------
// Kernel 3: per-(range, class) partial sum of class-k token vectors.
__global__ __launch_bounds__(256) void partials_kernel(
    const float* __restrict__ x, const int* __restrict__ pos,
    const int* __restrict__ cls_off, const int* __restrict__ cls_cnt,
    float* __restrict__ spart, int* __restrict__ cnt_range) {
    int bid = blockIdx.x;
    int k = bid & 63, j = bid >> 6;
    int t = threadIdx.x;
    int offk = cls_off[k], ck = cls_cnt[k];
    const int* pk = pos + offk;
    int lo = 0, hi = ck, v0 = j * RANGE;
    while (lo < hi) { int m = (lo + hi) >> 1; if (pk[m] < v0) lo = m + 1; else hi = m; }
    int is = lo;
    hi = ck; int v1 = (j + 1) * RANGE;
    while (lo < hi) { int m = (lo + hi) >> 1; if (pk[m] < v1) lo = m + 1; else hi = m; }
    int ie = lo;
    float4 a = {0, 0, 0, 0}, b = {0, 0, 0, 0};
    for (int i = is; i < ie; i++) {
        const float* r = x + (size_t)pk[i] * DIM;
        float4 xa = *(const float4*)(r + t * 4);
        float4 xb = *(const float4*)(r + 1024 + t * 4);
        a.x += xa.x; a.y += xa.y; a.z += xa.z; a.w += xa.w;
        b.x += xb.x; b.y += xb.y; b.z += xb.z; b.w += xb.w;
    }
    float* dst = spart + ((size_t)j * KCLS + k) * DIM;
    *(float4*)(dst + t * 4) = a;
    *(float4*)(dst + 1024 + t * 4) = b;
    if (t == 0) cnt_range[j * KCLS + k] = ie - is;
}

// ---------------------------------------------------------------------------
// Kernel 4: in-place exclusive scan over ranges -> boundary snapshots.
__global__ __launch_bounds__(256) void scan_kernel(
    const float* __restrict__ avgs, float* __restrict__ spart,
    const int* __restrict__ cnt_range, int* __restrict__ cnt_before) {
    int t = blockIdx.x * 256 + threadIdx.x;  // 32768 threads
    int k = t >> 9;
    int d4 = t & 511;
    int d = d4 * 4;
    float4 run = {0, 0, 0, 0};
    int cb = 0;
    float4 init = *(const float4*)(avgs + (size_t)k * DIM + d);
    for (int j = 0; j < JRANGES; j++) {
        size_t idx = ((size_t)j * KCLS + k) * DIM + d;
        float4 part = *(const float4*)(spart + idx);
        float4 w = (cb == 0) ? init : run;
        *(float4*)(spart + idx) = w;
        if (d4 == 0) cnt_before[j * KCLS + k] = cb;
        run.x += part.x; run.y += part.y; run.z += part.z; run.w += part.w;
        cb += cnt_range[j * KCLS + k];
    }
}

// ---------------------------------------------------------------------------
// Kernel 5 (v2): async-staged streaming main kernel.
// bid = g*32 + j  -> bid%8 == j%8: all 8 group-blocks of token-range j share
// one XCD's L2 (range = 4 MB = L2 size) -> ~7/8 of the 1 GB logical re-reads
// become L2 hits.
// Each wave holds 2 prototypes in 64 VGPRs (refreshed from the LDS fp32
// master only after its own class's events). Token vectors arrive via
// double-buffered global_load_lds chunks (4 tokens = 32 KB per buffer).
__global__ __launch_bounds__(256) void main_kernel(
    const float* __restrict__ x, const int* __restrict__ lab,
    const float* __restrict__ snap, const int* __restrict__ cnt_before,
    const float* __restrict__ vnorm2, const float* __restrict__ nvinv,
    float* __restrict__ out) {
    __shared__ float S[GRP][DIM];          // 64 KB  fp32 prototype master
    __shared__ float TB[2][C_TOK][DIM];    // 64 KB  staged token chunks
    __shared__ float norm2[GRP];
    __shared__ float rawd[GRP];
    __shared__ float wsum[4][GRP];
    __shared__ float nvs[RANGE];
    __shared__ float vn2s[RANGE];
    __shared__ unsigned char lbl[RANGE];

    int bid = blockIdx.x;
    int g = bid >> 5;          // class group 0..7
    int j = bid & 31;          // token range 0..31  (XCD = j%8 for all g)
    int g8 = g * GRP;
    int start = j * RANGE;
    int t = threadIdx.x;
    int lane = t & 63, wid = t >> 6;

    for (int i = t; i < RANGE; i += 256) {
        lbl[i] = (unsigned char)lab[start + i];
        nvs[i] = nvinv[start + i];
        vn2s[i] = vnorm2[start + i];
    }
#pragma unroll
    for (int c = 0; c < GRP; c++) {
        const float* srcp = snap + ((size_t)j * KCLS + g8 + c) * DIM;
        *(float4*)&S[c][t * 4] = *(const float4*)(srcp + t * 4);
        *(float4*)&S[c][1024 + t * 4] = *(const float4*)(srcp + 1024 + t * 4);
    }
    unsigned vmask = 0;
#pragma unroll
    for (int c = 0; c < GRP; c++)
        if (cnt_before[j * KCLS + g8 + c] == 0) vmask |= (1u << c);
    __syncthreads();

    // fresh norm^2 of the 8 prototypes
    float p[GRP];
#pragma unroll
    for (int c = 0; c < GRP; c++) p[c] = 0.f;
    for (int d = t; d < DIM; d += 256) {
#pragma unroll
        for (int c = 0; c < GRP; c++) { float v = S[c][d]; p[c] = fmaf(v, v, p[c]); }
    }
#pragma unroll
    for (int c = 0; c < GRP; c++) {
        float s = wred64(p[c]);
        if (lane == 0) wsum[wid][c] = s;
    }
    __syncthreads();
    if (t < GRP) norm2[t] = wsum[0][t] + wsum[1][t] + wsum[2][t] + wsum[3][t];
    __syncthreads();

    // wave-resident prototype pair
    int p0 = 2 * wid, p1 = 2 * wid + 1;
    float4 P0[8], P1[8];
#pragma unroll
    for (int it = 0; it < 8; it++) {
        P0[it] = *(const float4*)&S[p0][it * 256 + lane * 4];
        P1[it] = *(const float4*)&S[p1][it * 256 + lane * 4];
    }
    float n2r0 = norm2[p0], n2r1 = norm2[p1];

    // stage chunk 0 (wave w stages token w; 8 x 1KB async loads)
    {
        const float* srcv = x + (size_t)(start + wid) * DIM;
#pragma unroll
        for (int it = 0; it < 8; it++)
            __builtin_amdgcn_global_load_lds(
                (__attribute__((address_space(1))) void*)(srcv + it * 256 + lane * 4),
                (__attribute__((address_space(3))) void*)&TB[0][wid][it * 256],
                16, 0, 0);
    }
    __syncthreads();  // drains vmcnt: chunk 0 staged

    const int NCH = RANGE / C_TOK;
    int b = 0;
    for (int ch = 0; ch < NCH; ch++) {
        if (ch + 1 < NCH) {  // prefetch next chunk into other buffer
            const float* srcv = x + (size_t)(start + (ch + 1) * C_TOK + wid) * DIM;
#pragma unroll
            for (int it = 0; it < 8; it++)
                __builtin_amdgcn_global_load_lds(
                    (__attribute__((address_space(1))) void*)(srcv + it * 256 + lane * 4),
                    (__attribute__((address_space(3))) void*)&TB[1 - b][wid][it * 256],
                    16, 0, 0);
        }
        int base = ch * C_TOK;
        int ts = 0;
        while (ts < C_TOK) {
            int e = ts;
            while (e < C_TOK && (lbl[base + e] >> 3) != g) e++;
            int lastt = (e < C_TOK) ? e : (C_TOK - 1);
            float ed0 = 0.f, ed1 = 0.f;
            for (int tk = ts; tk <= lastt; tk++) {
                float a0 = 0.f, a1 = 0.f;
#pragma unroll
                for (int it = 0; it < 8; it++) {
                    float4 xv = *(const float4*)&TB[b][tk][it * 256 + lane * 4];
                    a0 = fmaf(xv.x, P0[it].x, a0); a0 = fmaf(xv.y, P0[it].y, a0);
                    a0 = fmaf(xv.z, P0[it].z, a0); a0 = fmaf(xv.w, P0[it].w, a0);
                    a1 = fmaf(xv.x, P1[it].x, a1); a1 = fmaf(xv.y, P1[it].y, a1);
                    a1 = fmaf(xv.z, P1[it].z, a1); a1 = fmaf(xv.w, P1[it].w, a1);
                }
                float d0 = wred64(a0), d1 = wred64(a1);
                ed0 = d0; ed1 = d1;
                if (lane == 0) {
                    int rel = base + tk;
                    float iv = nvs[rel];
                    float na0 = fmaxf(sqrtf(n2r0), EPS);
                    float na1 = fmaxf(sqrtf(n2r1), EPS);
                    float2 o2 = make_float2(d0 / na0 * iv, d1 / na1 * iv);
                    *(float2*)&out[(size_t)(start + rel) * KCLS + g8 + 2 * wid] = o2;
                }
            }
            if (e < C_TOK) {
                int ce = lbl[base + e] & 7;
                int rel = base + e;
                if (wid == (ce >> 1) && lane == 0) rawd[ce] = (ce & 1) ? ed1 : ed0;
                lds_barrier();  // rawd visible; no vmcnt drain (prefetch stays in flight)
                bool vg = (vmask >> ce) & 1u;
                const float* v = &TB[b][e][0];
                float4 xa = *(const float4*)(v + t * 4);
                float4 xb = *(const float4*)(v + 1024 + t * 4);
                if (vg) {
                    *(float4*)&S[ce][t * 4] = xa;
                    *(float4*)&S[ce][1024 + t * 4] = xb;
                    if (t == 0) norm2[ce] = vn2s[rel];
                } else {
                    float4 sa = *(float4*)&S[ce][t * 4];
                    float4 sb = *(float4*)&S[ce][1024 + t * 4];
                    sa.x += xa.x; sa.y += xa.y; sa.z += xa.z; sa.w += xa.w;
                    sb.x += xb.x; sb.y += xb.y; sb.z += xb.z; sb.w += xb.w;
                    *(float4*)&S[ce][t * 4] = sa;
                    *(float4*)&S[ce][1024 + t * 4] = sb;
                    if (t == 0) norm2[ce] += 2.0f * rawd[ce] + vn2s[rel];
                }
                vmask &= ~(1u << ce);
                lds_barrier();  // S/norm2 update visible
                if (wid == (ce >> 1)) {  // owning wave refreshes its register proto
                    if ((ce & 1) == 0) {
#pragma unroll
                        for (int it = 0; it < 8; it++)
                            P0[it] = *(const float4*)&S[ce][it * 256 + lane * 4];
                        n2r0 = norm2[ce];
                    } else {
#pragma unroll
                        for (int it = 0; it < 8; it++)
                            P1[it] = *(const float4*)&S[ce][it * 256 + lane * 4];
                        n2r1 = norm2[ce];
                    }
                }
            }
            ts = e + 1;
        }
        __syncthreads();  // drains vmcnt: next chunk fully staged; TB[b] free for reuse
        b ^= 1;
    }
}

// ---------------------------------------------------------------------------
extern "C" void kernel_launch(void* const* d_in, const int* in_sizes, int n_in,
                              void* d_out, int out_size, void* d_ws, size_t ws_size,
                              hipStream_t stream) {
    const float* inputs = (const float*)d_in[0];
    const float* class_avgs = (const float*)d_in[1];
    const int* labels_raw = (const int*)d_in[2];
    float* out = (float*)d_out;
    char* ws = (char*)d_ws;

    size_t off = 0;
    int* lab = (int*)(ws + off);        off += (size_t)N_TOK * 4;
    float* vnorm2 = (float*)(ws + off); off += (size_t)N_TOK * 4;
    float* nvinv = (float*)(ws + off);  off += (size_t)N_TOK * 4;
    int* pos = (int*)(ws + off);        off += (size_t)N_TOK * 4;
    int* cls_off = (int*)(ws + off);    off += 256;
    int* cls_cnt = (int*)(ws + off);    off += 256;
    int* cnt_range = (int*)(ws + off);  off += (size_t)JRANGES * KCLS * 4;
    int* cnt_before = (int*)(ws + off); off += (size_t)JRANGES * KCLS * 4;
    off = (off + 255) & ~(size_t)255;
    float* spart = (float*)(ws + off);  // JRANGES*KCLS*DIM floats = 16 MB

    fix_labels_kernel<<<1, 256, 0, stream>>>(labels_raw, lab);
    norms_kernel<<<N_TOK / 4, 256, 0, stream>>>(inputs, vnorm2, nvinv);
    bucket_kernel<<<1, 1024, 0, stream>>>(lab, pos, cls_off, cls_cnt);
    partials_kernel<<<JRANGES * KCLS, 256, 0, stream>>>(inputs, pos, cls_off,
                                                        cls_cnt, spart, cnt_range);
    scan_kernel<<<(KCLS * (DIM / 4)) / 256, 256, 0, stream>>>(class_avgs, spart,
                                                              cnt_range, cnt_before);
    main_kernel<<<NGRP * JRANGES, 256, 0, stream>>>(inputs, lab, spart, cnt_before,
                                                    vnorm2, nvinv, out);
}

// Round 4
// 326.483 us; speedup vs baseline: 3.3553x; 2.0994x over previous
//
#include <hip/hip_runtime.h>

#define N_TOK 16384
#define DIM 2048
#define KCLS 64
#define JRANGES 32
#define RANGE 512   // N_TOK / JRANGES
#define GRP 8       // classes per block group
#define NGRP 8      // KCLS / GRP
#define C_TOK 8     // tokens per staged chunk (== waves per block)
#define EPS 1e-8f

__device__ __forceinline__ float wred64(float v) {
#pragma unroll
    for (int o = 32; o > 0; o >>= 1) v += __shfl_xor(v, o, 64);
    return v;
}

// Canonical GCN wave64 sum-reduction on the VALU pipe (DPP), total lands in
// lane 63. row_shr:1/2/4/8 then row_bcast15, row_bcast31.
__device__ __forceinline__ float dpp_sum64(float x) {
    x += __int_as_float(__builtin_amdgcn_update_dpp(0, __float_as_int(x), 0x111, 0xf, 0xf, true));
    x += __int_as_float(__builtin_amdgcn_update_dpp(0, __float_as_int(x), 0x112, 0xf, 0xf, true));
    x += __int_as_float(__builtin_amdgcn_update_dpp(0, __float_as_int(x), 0x114, 0xf, 0xf, true));
    x += __int_as_float(__builtin_amdgcn_update_dpp(0, __float_as_int(x), 0x118, 0xf, 0xf, true));
    x += __int_as_float(__builtin_amdgcn_update_dpp(0, __float_as_int(x), 0x142, 0xf, 0xf, true));
    x += __int_as_float(__builtin_amdgcn_update_dpp(0, __float_as_int(x), 0x143, 0xf, 0xf, true));
    return x;  // valid in lane 63 only
}

__device__ __forceinline__ float bcast63(float x) {
    return __int_as_float(__builtin_amdgcn_readlane(__float_as_int(x), 63));
}

// ---------------------------------------------------------------------------
// Kernel 0: sniff labels dtype (int64 vs int32) and normalize to int32 in ws.
__global__ __launch_bounds__(1024) void fix_labels_kernel(
    const int* __restrict__ raw, int* __restrict__ lab) {
    __shared__ int not64;
    int t = threadIdx.x;
    if (t == 0) not64 = 0;
    __syncthreads();
    int lo = raw[2 * t], hi = raw[2 * t + 1];
    if (hi != 0 || lo < 0 || lo >= KCLS) atomicOr(&not64, 1);
    __syncthreads();
    int is64 = !not64;
    for (int n = t; n < N_TOK; n += 1024)
        lab[n] = is64 ? raw[2 * n] : raw[n];
}

// ---------------------------------------------------------------------------
// Kernel 1: per-token squared norm and inverse clamped norm. One wave/token.
__global__ __launch_bounds__(256) void norms_kernel(
    const float* __restrict__ x, float* __restrict__ vnorm2,
    float* __restrict__ nvinv) {
    int wid = threadIdx.x >> 6, lane = threadIdx.x & 63;
    int n = blockIdx.x * 4 + wid;
    const float* v = x + (size_t)n * DIM;
    float p = 0.f;
#pragma unroll
    for (int it = 0; it < 8; it++) {
        int d = it * 256 + lane * 4;
        float4 a = *(const float4*)(v + d);
        p = fmaf(a.x, a.x, p); p = fmaf(a.y, a.y, p);
        p = fmaf(a.z, a.z, p); p = fmaf(a.w, a.w, p);
    }
    p = wred64(p);
    if (lane == 0) {
        vnorm2[n] = p;
        nvinv[n] = 1.0f / fmaxf(sqrtf(p), EPS);
    }
}

// ---------------------------------------------------------------------------
// Kernel 2: per-(range, class) partial sum of class-k token vectors.
// No global bucketing needed: each block scans its range's 512 labels in LDS.
__global__ __launch_bounds__(256) void partials_kernel(
    const float* __restrict__ x, const int* __restrict__ lab,
    float* __restrict__ spart, int* __restrict__ cnt_range) {
    int bid = blockIdx.x;
    int k = bid & 63, j = bid >> 6;
    int t = threadIdx.x;
    __shared__ int ll[RANGE];
    __shared__ short ml[RANGE];
    __shared__ int nm_s;
    for (int i = t; i < RANGE; i += 256) ll[i] = lab[j * RANGE + i];
    __syncthreads();
    if (t == 0) {
        int nm = 0;
        for (int i = 0; i < RANGE; i++)
            if (ll[i] == k) ml[nm++] = (short)i;
        nm_s = nm;
        cnt_range[j * KCLS + k] = nm;
    }
    __syncthreads();
    int nm = nm_s;
    float4 a = {0, 0, 0, 0}, b4 = {0, 0, 0, 0};
    for (int m = 0; m < nm; m++) {
        const float* r = x + (size_t)(j * RANGE + (int)ml[m]) * DIM;
        float4 xa = *(const float4*)(r + t * 4);
        float4 xb = *(const float4*)(r + 1024 + t * 4);
        a.x += xa.x; a.y += xa.y; a.z += xa.z; a.w += xa.w;
        b4.x += xb.x; b4.y += xb.y; b4.z += xb.z; b4.w += xb.w;
    }
    float* dst = spart + ((size_t)j * KCLS + k) * DIM;
    *(float4*)(dst + t * 4) = a;
    *(float4*)(dst + 1024 + t * 4) = b4;
}

// ---------------------------------------------------------------------------
// Kernel 3: in-place exclusive scan over ranges -> boundary snapshots.
__global__ __launch_bounds__(256) void scan_kernel(
    const float* __restrict__ avgs, float* __restrict__ spart,
    const int* __restrict__ cnt_range, int* __restrict__ cnt_before) {
    int t = blockIdx.x * 256 + threadIdx.x;  // 32768 threads
    int k = t >> 9;
    int d4 = t & 511;
    int d = d4 * 4;
    float4 run = {0, 0, 0, 0};
    int cb = 0;
    float4 init = *(const float4*)(avgs + (size_t)k * DIM + d);
    for (int j = 0; j < JRANGES; j++) {
        size_t idx = ((size_t)j * KCLS + k) * DIM + d;
        float4 part = *(const float4*)(spart + idx);
        float4 w = (cb == 0) ? init : run;
        *(float4*)(spart + idx) = w;
        if (d4 == 0) cnt_before[j * KCLS + k] = cb;
        run.x += part.x; run.y += part.y; run.z += part.z; run.w += part.w;
        cb += cnt_range[j * KCLS + k];
    }
}

// ---------------------------------------------------------------------------
// Kernel 4 (v3): barrier-free main kernel.
// 512 threads = 8 waves. Waves 0-3 own proto quad A (classes g8..g8+3),
// waves 4-7 quad B. Each wave holds its 4 prototypes in 128 VGPRs plus
// replicated norm^2 scalars. Wave w outputs tokens {2*(w&3), 2*(w&3)+1} of
// each 8-token chunk and additionally replays every event token of its quad
// (identical updates in identical order -> wave copies never diverge, zero
// cross-wave sync). Dot reductions on the VALU pipe via DPP.
// bid = g*32 + j keeps bid%8 == j%8: the 8 g-blocks of range j share an XCD L2.
__global__ __launch_bounds__(512, 2) void main_kernel(
    const float* __restrict__ x, const int* __restrict__ lab,
    const float* __restrict__ snap, const int* __restrict__ cnt_before,
    const float* __restrict__ vnorm2, const float* __restrict__ nvinv,
    float* __restrict__ out) {
    __shared__ float TB[2][C_TOK][DIM];    // 128 KB staged token chunks
    __shared__ float nvs[RANGE];
    __shared__ float vn2s[RANGE];
    __shared__ unsigned char lbl[RANGE];

    int bid = blockIdx.x;
    int g = bid >> 5;          // class group 0..7
    int j = bid & 31;          // token range 0..31
    int start = j * RANGE;
    int t = threadIdx.x;
    int lane = t & 63, wid = t >> 6;
    int qd = wid >> 2;                 // proto quad 0/1
    int qtr = wid & 3;                 // token quarter 0..3
    int qbase = g * GRP + qd * 4;      // first class of this wave's quad
    int myq2 = (g << 1) | qd;          // label>>2 signature of quad

    for (int i = t; i < RANGE; i += 512) {
        lbl[i] = (unsigned char)lab[start + i];
        nvs[i] = nvinv[start + i];
        vn2s[i] = vnorm2[start + i];
    }

    // 4 register-resident prototypes + norms
    float4 P[4][8];
#pragma unroll
    for (int q = 0; q < 4; q++) {
        const float* sp = snap + ((size_t)j * KCLS + qbase + q) * DIM;
#pragma unroll
        for (int it = 0; it < 8; it++)
            P[q][it] = *(const float4*)(sp + it * 256 + lane * 4);
    }
    float n2[4], inv_na[4];
#pragma unroll
    for (int q = 0; q < 4; q++) {
        float s = 0.f;
#pragma unroll
        for (int it = 0; it < 8; it++) {
            float4 pp = P[q][it];
            s = fmaf(pp.x, pp.x, s); s = fmaf(pp.y, pp.y, s);
            s = fmaf(pp.z, pp.z, s); s = fmaf(pp.w, pp.w, s);
        }
        n2[q] = bcast63(dpp_sum64(s));
        inv_na[q] = 1.0f / fmaxf(sqrtf(n2[q]), EPS);
    }
    unsigned vmask = 0;
#pragma unroll
    for (int q = 0; q < 4; q++)
        if (cnt_before[j * KCLS + qbase + q] == 0) vmask |= (1u << q);

    // stage chunk 0: wave w stages token w (8 x 1KB async loads)
    {
        const float* srcv = x + (size_t)(start + wid) * DIM;
#pragma unroll
        for (int it = 0; it < 8; it++)
            __builtin_amdgcn_global_load_lds(
                (__attribute__((address_space(1))) void*)(srcv + it * 256 + lane * 4),
                (__attribute__((address_space(3))) void*)&TB[0][wid][it * 256],
                16, 0, 0);
    }
    __syncthreads();  // lbl/nvs staged + chunk 0 resident

    const int NCH = RANGE / C_TOK;  // 64
    int b = 0;
    for (int ch = 0; ch < NCH; ch++) {
        if (ch + 1 < NCH) {  // prefetch next chunk into other buffer
            const float* srcv = x + (size_t)(start + (ch + 1) * C_TOK + wid) * DIM;
#pragma unroll
            for (int it = 0; it < 8; it++)
                __builtin_amdgcn_global_load_lds(
                    (__attribute__((address_space(1))) void*)(srcv + it * 256 + lane * 4),
                    (__attribute__((address_space(3))) void*)&TB[1 - b][wid][it * 256],
                    16, 0, 0);
        }
        int base = ch * C_TOK;
#pragma unroll 1
        for (int tok = 0; tok < C_TOK; tok++) {
            int lb = lbl[base + tok];
            bool ev = ((lb >> 2) == myq2);        // event of this wave's quad
            bool asg = ((tok >> 1) == qtr);       // this wave's output token
            if (!(ev || asg)) continue;

            float4 xv[8];
#pragma unroll
            for (int it = 0; it < 8; it++)
                xv[it] = *(const float4*)&TB[b][tok][it * 256 + lane * 4];

            float ds[4] = {0.f, 0.f, 0.f, 0.f};
#pragma unroll
            for (int it = 0; it < 8; it++) {
#pragma unroll
                for (int q = 0; q < 4; q++) {
                    ds[q] = fmaf(xv[it].x, P[q][it].x, ds[q]);
                    ds[q] = fmaf(xv[it].y, P[q][it].y, ds[q]);
                    ds[q] = fmaf(xv[it].z, P[q][it].z, ds[q]);
                    ds[q] = fmaf(xv[it].w, P[q][it].w, ds[q]);
                }
            }
#pragma unroll
            for (int q = 0; q < 4; q++) ds[q] = dpp_sum64(ds[q]);

            int rel = base + tok;
            if (asg) {
                float iv = nvs[rel];
                float4 o;
                o.x = ds[0] * inv_na[0] * iv;
                o.y = ds[1] * inv_na[1] * iv;
                o.z = ds[2] * inv_na[2] * iv;
                o.w = ds[3] * inv_na[3] * iv;
                if (lane == 63)
                    *(float4*)&out[(size_t)(start + rel) * KCLS + qbase] = o;
            }
            if (ev) {
                int ceq = lb & 3;
                float vn2 = vn2s[rel];
#pragma unroll
                for (int q = 0; q < 4; q++) {
                    if (q != ceq) continue;  // wave-uniform; q stays compile-time
                    float rd = bcast63(ds[q]);
                    if ((vmask >> q) & 1u) {  // first-ever token of this class
#pragma unroll
                        for (int it = 0; it < 8; it++) P[q][it] = xv[it];
                        n2[q] = vn2;
                    } else {
#pragma unroll
                        for (int it = 0; it < 8; it++) {
                            P[q][it].x += xv[it].x; P[q][it].y += xv[it].y;
                            P[q][it].z += xv[it].z; P[q][it].w += xv[it].w;
                        }
                        n2[q] += 2.0f * rd + vn2;
                    }
                    inv_na[q] = 1.0f / fmaxf(sqrtf(n2[q]), EPS);
                }
                vmask &= ~(1u << ceq);
            }
        }
        __syncthreads();  // next chunk fully staged; TB[b] free for reuse
        b ^= 1;
    }
}

// ---------------------------------------------------------------------------
extern "C" void kernel_launch(void* const* d_in, const int* in_sizes, int n_in,
                              void* d_out, int out_size, void* d_ws, size_t ws_size,
                              hipStream_t stream) {
    const float* inputs = (const float*)d_in[0];
    const float* class_avgs = (const float*)d_in[1];
    const int* labels_raw = (const int*)d_in[2];
    float* out = (float*)d_out;
    char* ws = (char*)d_ws;

    size_t off = 0;
    int* lab = (int*)(ws + off);        off += (size_t)N_TOK * 4;
    float* vnorm2 = (float*)(ws + off); off += (size_t)N_TOK * 4;
    float* nvinv = (float*)(ws + off);  off += (size_t)N_TOK * 4;
    int* cnt_range = (int*)(ws + off);  off += (size_t)JRANGES * KCLS * 4;
    int* cnt_before = (int*)(ws + off); off += (size_t)JRANGES * KCLS * 4;
    off = (off + 255) & ~(size_t)255;
    float* spart = (float*)(ws + off);  // JRANGES*KCLS*DIM floats = 16 MB

    fix_labels_kernel<<<1, 1024, 0, stream>>>(labels_raw, lab);
    norms_kernel<<<N_TOK / 4, 256, 0, stream>>>(inputs, vnorm2, nvinv);
    partials_kernel<<<JRANGES * KCLS, 256, 0, stream>>>(inputs, lab, spart, cnt_range);
    scan_kernel<<<(KCLS * (DIM / 4)) / 256, 256, 0, stream>>>(class_avgs, spart,
                                                              cnt_range, cnt_before);
    main_kernel<<<NGRP * JRANGES, 512, 0, stream>>>(inputs, lab, spart, cnt_before,
                                                    vnorm2, nvinv, out);
}